// Round 11
// baseline (879.784 us; speedup 1.0000x reference)
//
#include <hip/hip_runtime.h>
#include <hip/hip_cooperative_groups.h>

namespace cg = cooperative_groups;

#define N_NODES 50000
#define N_EDGES 800000
#define NBUCK 196                   // buckets of 256 nodes: bucket = dst >> 8
#define CAP 4608                    // fixed bucket capacity (mean 4082 -> 8 sigma headroom)
#define CSTRIDE 16                  // cursor padding: one cursor per 64B cache line
#define EPB 4096                    // edges per stripe-block (measured best)
#define NSTRIPE ((N_EDGES + EPB - 1) / EPB)  // 196
#define BLK 512                     // 8 waves per block
#define SLPB ((N_NODES + 127) / 128)         // 391 SLP tiles (128 rows each)
#define WSPLU ((73728 - 16384) / BLK)        // 112 weight-split chunks
#define NTILE (N_NODES / 16)                 // 3125 layer tiles (exact)
#define MAXGRID 1024                         // 4 blocks/CU x 256 CU upper bound

typedef __attribute__((ext_vector_type(8))) short short8;
typedef __attribute__((ext_vector_type(4))) float float4v;

__device__ inline unsigned short f2bf(float f) {
    unsigned u = __float_as_uint(f);
    unsigned r = u + 0x7fff + ((u >> 16) & 1);
    return (unsigned short)(r >> 16);
}
__device__ inline float bf2f(unsigned short h) {
    return __uint_as_float(((unsigned)h) << 16);
}

// split 8 contiguous fp32 into bf16 hi/lo fragments
__device__ __forceinline__ void split8(const float* p, short8& hi8, short8& lo8) {
    float4 f0 = *(const float4*)p;
    float4 f1 = *(const float4*)(p + 4);
    float fv[8] = {f0.x, f0.y, f0.z, f0.w, f1.x, f1.y, f1.z, f1.w};
#pragma unroll
    for (int j = 0; j < 8; j++) {
        unsigned short hh = f2bf(fv[j]);
        hi8[j] = (short)hh;
        lo8[j] = (short)f2bf(fv[j] - bf2f(hh));
    }
}

// ---------------- deep-ILP neighbor gather (16 edges in flight) ----------------

__device__ __forceinline__ void gather_sum(const unsigned short* bf, const int* esrc,
                                           int beg, int end, int eg, int fo, float a0[8]) {
    float a1[8], a2[8], a3[8];
#pragma unroll
    for (int j = 0; j < 8; j++) { a0[j] = 0.f; a1[j] = 0.f; a2[j] = 0.f; a3[j] = 0.f; }
    int e = beg;
    for (; e + 15 < end; e += 16) {
        int s0 = esrc[e + eg];
        int s1 = esrc[e + 4 + eg];
        int s2 = esrc[e + 8 + eg];
        int s3 = esrc[e + 12 + eg];
        short8 v0 = *(const short8*)(bf + (size_t)s0 * 128 + fo * 8);
        short8 v1 = *(const short8*)(bf + (size_t)s1 * 128 + fo * 8);
        short8 v2 = *(const short8*)(bf + (size_t)s2 * 128 + fo * 8);
        short8 v3 = *(const short8*)(bf + (size_t)s3 * 128 + fo * 8);
#pragma unroll
        for (int j = 0; j < 8; j++) a0[j] += bf2f((unsigned short)v0[j]);
#pragma unroll
        for (int j = 0; j < 8; j++) a1[j] += bf2f((unsigned short)v1[j]);
#pragma unroll
        for (int j = 0; j < 8; j++) a2[j] += bf2f((unsigned short)v2[j]);
#pragma unroll
        for (int j = 0; j < 8; j++) a3[j] += bf2f((unsigned short)v3[j]);
    }
    if (e + 7 < end) {
        int s0 = esrc[e + eg];
        int s1 = esrc[e + 4 + eg];
        short8 v0 = *(const short8*)(bf + (size_t)s0 * 128 + fo * 8);
        short8 v1 = *(const short8*)(bf + (size_t)s1 * 128 + fo * 8);
#pragma unroll
        for (int j = 0; j < 8; j++) a0[j] += bf2f((unsigned short)v0[j]);
#pragma unroll
        for (int j = 0; j < 8; j++) a1[j] += bf2f((unsigned short)v1[j]);
        e += 8;
    }
    if (e + 3 < end) {
        int s = esrc[e + eg];
        short8 v = *(const short8*)(bf + (size_t)s * 128 + fo * 8);
#pragma unroll
        for (int j = 0; j < 8; j++) a2[j] += bf2f((unsigned short)v[j]);
        e += 4;
    }
    int rem = end - e;
    if (eg < rem) {
        int s = esrc[e + eg];
        short8 v = *(const short8*)(bf + (size_t)s * 128 + fo * 8);
#pragma unroll
        for (int j = 0; j < 8; j++) a3[j] += bf2f((unsigned short)v[j]);
    }
#pragma unroll
    for (int j = 0; j < 8; j++) {
        float s = (a0[j] + a1[j]) + (a2[j] + a3[j]);
        s += __shfl_xor(s, 16);
        s += __shfl_xor(s, 32);
        a0[j] = s;
    }
}

// ---------------- phase 0a: binA stripe (512 threads) ----------------

__device__ void binA_stripe(int sb, const int* src, const int* dst, int* cursor,
                            int* packed, int* lcount, int* lbase) {
    int t = threadIdx.x;
    if (t < 256) lcount[t] = 0;
    __syncthreads();
    int base = sb * EPB + t;
    int d[EPB / BLK];  // 8
#pragma unroll
    for (int k = 0; k < EPB / BLK; k++) {
        int i = base + k * BLK;
        d[k] = (i < N_EDGES) ? dst[i] : -1;
        if (d[k] >= 0) atomicAdd(&lcount[((unsigned)d[k]) >> 8], 1);
    }
    __syncthreads();
    if (t < NBUCK) {
        lbase[t] = t * CAP + atomicAdd(&cursor[t * CSTRIDE], lcount[t]);
        lcount[t] = 0;
    }
    __syncthreads();
#pragma unroll
    for (int k = 0; k < EPB / BLK; k++) {
        if (d[k] >= 0) {
            int i = base + k * BLK;
            int wb = ((unsigned)d[k]) >> 8;
            int p = lbase[wb] + atomicAdd(&lcount[wb], 1);
            if (p < (wb + 1) * CAP) packed[p] = ((d[k] & 255) << 16) | src[i];
        }
    }
    __syncthreads();
}

// ---------------- phase 0b: SLP GEMM tile (128 rows, 8 waves) ----------------

__device__ void slp_tile(int tile, const float* X, const float* fcW, const float* fcb,
                         float* h, unsigned short* hbf) {
    int wave = threadIdx.x >> 6;
    int lane = threadIdx.x & 63;
    int m = lane & 15;
    int quad = lane >> 4;
    int r0 = tile * 128 + wave * 16;
    int rowA = r0 + m;
    if (rowA >= N_NODES) rowA = N_NODES - 1;  // clamp loads; stores guarded

    short8 ahi[4], alo[4];
    const float* arow = X + (size_t)rowA * 128 + quad * 8;
#pragma unroll
    for (int kc = 0; kc < 4; kc++) split8(arow + kc * 32, ahi[kc], alo[kc]);

#pragma unroll
    for (int nt = 0; nt < 8; nt++) {
        int n = nt * 16 + m;
        const float* brow = fcW + (size_t)n * 128 + quad * 8;
        float4v acc = {0.f, 0.f, 0.f, 0.f};
#pragma unroll
        for (int kc = 0; kc < 4; kc++) {
            short8 bh, bl;
            split8(brow + kc * 32, bh, bl);
            acc = __builtin_amdgcn_mfma_f32_16x16x32_bf16(ahi[kc], bh, acc, 0, 0, 0);
            acc = __builtin_amdgcn_mfma_f32_16x16x32_bf16(alo[kc], bh, acc, 0, 0, 0);
            acc = __builtin_amdgcn_mfma_f32_16x16x32_bf16(ahi[kc], bl, acc, 0, 0, 0);
        }
        float bv = fcb[n];
#pragma unroll
        for (int i = 0; i < 4; i++) {
            int r = r0 + quad * 4 + i;
            if (r < N_NODES) {
                float v = fmaxf(acc[i] + bv, 0.f);
                h[(size_t)r * 128 + n] = v;
                hbf[(size_t)r * 128 + n] = f2bf(v);
            }
        }
    }
}

// ---------------- phase 1: binB bucket (512 threads; scan arrays are 256) ----------

__device__ void binB_bucket(int b, const int* packed, const int* cursor, int* row_ptr,
                            int* esrc, int* sm, int* cntS, int* curs) {
    int t = threadIdx.x;
    bool act = t < 256;
    int cnt = (act && t < NBUCK) ? cursor[t * CSTRIDE] : 0;
    if (act) { cntS[t] = cnt; sm[t] = cnt; }
    __syncthreads();
    for (int o = 1; o < 256; o <<= 1) {
        int x = act ? sm[t] : 0;
        int a = (act && t >= o) ? sm[t - o] : 0;
        __syncthreads();
        if (act) sm[t] = x + a;
        __syncthreads();
    }
    int w0 = sm[b] - cntS[b];
    int mycnt = cntS[b];
    if (b == NBUCK - 1 && t == 0) row_ptr[N_NODES] = sm[NBUCK - 1];
    __syncthreads();
    int e0r = b * CAP, e1r = b * CAP + mycnt;
    if (act) curs[t] = 0;
    __syncthreads();
    for (int i = e0r + t; i < e1r; i += BLK) atomicAdd(&curs[((unsigned)packed[i]) >> 16], 1);
    __syncthreads();
    int v = act ? curs[t] : 0;
    __syncthreads();
    if (act) sm[t] = v;
    __syncthreads();
    for (int o = 1; o < 256; o <<= 1) {
        int x = act ? sm[t] : 0;
        int a = (act && t >= o) ? sm[t - o] : 0;
        __syncthreads();
        if (act) sm[t] = x + a;
        __syncthreads();
    }
    if (act) {
        int excl = sm[t] - v;
        curs[t] = excl;
        int node = b * 256 + t;
        if (node < N_NODES) row_ptr[node] = w0 + excl;
    }
    __syncthreads();
    for (int i = e0r + t; i < e1r; i += BLK) {
        unsigned w = (unsigned)packed[i];
        int p = atomicAdd(&curs[w >> 16], 1);
        esrc[w0 + p] = (int)(w & 0xFFFFu);
    }
    __syncthreads();
}

// ---------------- layer tile: r7's proven 8-wave body (16 nodes/tile) ----------

template <bool LAST>
__device__ void layer_tile(int tile, float* hio, const unsigned short* bfin,
                           unsigned short* bfout, const int* row_ptr, const int* esrc,
                           const float* eps, int layer, const unsigned short* Whi,
                           const unsigned short* Wlo, const float* bias,
                           const unsigned short* Lhi, const unsigned short* Llo,
                           float* g, unsigned short* gbf, unsigned* lds_hi,
                           unsigned* lds_lo) {
    int tid = threadIdx.x;
    int wv = tid >> 6;
    int lane = tid & 63;
    int eg = lane >> 4;
    int fo = lane & 15;
    int nb = tile * 16;
    float ep = 1.0f + eps[layer];

    // phase 1: wave wv gathers nodes wv and wv+8 (2 serial, 16 edges in flight)
#pragma unroll
    for (int half = 0; half < 2; half++) {
        int r = wv + half * 8;
        int node = nb + r;
        int beg = __builtin_amdgcn_readfirstlane(row_ptr[node]);
        int end = __builtin_amdgcn_readfirstlane(row_ptr[node + 1]);
        float a0[8];
        gather_sum(bfin, esrc, beg, end, eg, fo, a0);
        if (eg == 0) {
            int d = end - beg;
            float inv = (d > 0) ? 1.0f / (float)d : 0.0f;
            const float* hr = hio + (size_t)node * 128 + fo * 8;
            float4 h0 = *(const float4*)hr;
            float4 h1 = *(const float4*)(hr + 4);
            float hv[8] = {h0.x, h0.y, h0.z, h0.w, h1.x, h1.y, h1.z, h1.w};
            unsigned hip[4], lop[4];
#pragma unroll
            for (int jj = 0; jj < 4; jj++) {
                float ux = ep * hv[2 * jj] + a0[2 * jj] * inv;
                float uy = ep * hv[2 * jj + 1] + a0[2 * jj + 1] * inv;
                unsigned short uh0 = f2bf(ux), uh1 = f2bf(uy);
                hip[jj] = (unsigned)uh0 | ((unsigned)uh1 << 16);
                lop[jj] = (unsigned)f2bf(ux - bf2f(uh0)) | ((unsigned)f2bf(uy - bf2f(uh1)) << 16);
            }
            int grp = fo ^ (r & 7);
            *(uint4*)&lds_hi[r * 64 + grp * 4] = make_uint4(hip[0], hip[1], hip[2], hip[3]);
            *(uint4*)&lds_lo[r * 64 + grp * 4] = make_uint4(lop[0], lop[1], lop[2], lop[3]);
        }
    }
    __syncthreads();

    // phase 2: wave wv owns col-tile wv (16 cols)
    int m = lane & 15;
    int quad = lane >> 4;
    short8 ahi[4], alo[4];
#pragma unroll
    for (int kc = 0; kc < 4; kc++) {
        int grp = (quad + kc * 4) ^ (m & 7);
        ahi[kc] = *(const short8*)&lds_hi[m * 64 + grp * 4];
        alo[kc] = *(const short8*)&lds_lo[m * 64 + grp * 4];
    }
    int n = wv * 16 + m;
    const unsigned short* bhp = Whi + (size_t)n * 128 + quad * 8;
    const unsigned short* blp = Wlo + (size_t)n * 128 + quad * 8;
    float4v acc = {0.f, 0.f, 0.f, 0.f};
#pragma unroll
    for (int kc = 0; kc < 4; kc++) {
        short8 bh = *(const short8*)(bhp + kc * 32);
        short8 bl = *(const short8*)(blp + kc * 32);
        acc = __builtin_amdgcn_mfma_f32_16x16x32_bf16(ahi[kc], bh, acc, 0, 0, 0);
        acc = __builtin_amdgcn_mfma_f32_16x16x32_bf16(alo[kc], bh, acc, 0, 0, 0);
        acc = __builtin_amdgcn_mfma_f32_16x16x32_bf16(ahi[kc], bl, acc, 0, 0, 0);
    }
    float bv = bias[n];

    if (!LAST) {
#pragma unroll
        for (int i = 0; i < 4; i++) {
            int rg = nb + quad * 4 + i;
            float v = fmaxf(acc[i] + bv, 0.f);
            hio[(size_t)rg * 128 + n] = v;
            bfout[(size_t)rg * 128 + n] = f2bf(v);
        }
        __syncthreads();  // LDS reuse guard before next tile
    } else {
        // h3 back into LDS (barrier first: phase-2 reads must drain)
        __syncthreads();
        unsigned short* lh = (unsigned short*)lds_hi;
        unsigned short* ll = (unsigned short*)lds_lo;
#pragma unroll
        for (int i = 0; i < 4; i++) {
            int rl = quad * 4 + i;
            float v = fmaxf(acc[i] + bv, 0.f);
            unsigned short vh = f2bf(v);
            unsigned short vl = f2bf(v - bf2f(vh));
            int gidx = (n >> 3) ^ (rl & 7);
            int us = rl * 128 + gidx * 8 + (n & 7);
            lh[us] = vh;
            ll[us] = vl;
        }
        __syncthreads();
        // phase 3: waves 0-3 -> g = h3 @ Wl^T (64 cols)
        if (wv < 4) {
            short8 a2h[4], a2l[4];
#pragma unroll
            for (int kc = 0; kc < 4; kc++) {
                int grp = (quad + kc * 4) ^ (m & 7);
                a2h[kc] = *(const short8*)&lds_hi[m * 64 + grp * 4];
                a2l[kc] = *(const short8*)&lds_lo[m * 64 + grp * 4];
            }
            int n2 = wv * 16 + m;
            const unsigned short* lhp = Lhi + (size_t)n2 * 128 + quad * 8;
            const unsigned short* llp = Llo + (size_t)n2 * 128 + quad * 8;
            float4v a2 = {0.f, 0.f, 0.f, 0.f};
#pragma unroll
            for (int kc = 0; kc < 4; kc++) {
                short8 bh = *(const short8*)(lhp + kc * 32);
                short8 bl = *(const short8*)(llp + kc * 32);
                a2 = __builtin_amdgcn_mfma_f32_16x16x32_bf16(a2h[kc], bh, a2, 0, 0, 0);
                a2 = __builtin_amdgcn_mfma_f32_16x16x32_bf16(a2l[kc], bh, a2, 0, 0, 0);
                a2 = __builtin_amdgcn_mfma_f32_16x16x32_bf16(a2h[kc], bl, a2, 0, 0, 0);
            }
#pragma unroll
            for (int i = 0; i < 4; i++) {
                int rg = nb + quad * 4 + i;
                float v = a2[i];
                g[(size_t)rg * 64 + n2] = v;
                gbf[(size_t)rg * 64 + n2] = f2bf(v);
            }
        }
        __syncthreads();  // LDS reuse guard before next tile
    }
}

// ---------------- final phase: out = (1+eps3)*g + mean(g) + bl (one wave/node) ----

__device__ void agg64_node(int node, const float* g, const unsigned short* gbf,
                           const int* row_ptr, const int* esrc, const float* eps,
                           const float* bl, float* out) {
    int lane = threadIdx.x & 63;
    int beg = __builtin_amdgcn_readfirstlane(row_ptr[node]);
    int end = __builtin_amdgcn_readfirstlane(row_ptr[node + 1]);
    int eg = lane >> 3;
    int fo = lane & 7;

    float a0[8] = {0.f, 0.f, 0.f, 0.f, 0.f, 0.f, 0.f, 0.f};
    float a1[8] = {0.f, 0.f, 0.f, 0.f, 0.f, 0.f, 0.f, 0.f};
    float a2[8] = {0.f, 0.f, 0.f, 0.f, 0.f, 0.f, 0.f, 0.f};
    float a3[8] = {0.f, 0.f, 0.f, 0.f, 0.f, 0.f, 0.f, 0.f};
    int e = beg;
    for (; e + 31 < end; e += 32) {
        int s0 = esrc[e + eg];
        int s1 = esrc[e + 8 + eg];
        int s2 = esrc[e + 16 + eg];
        int s3 = esrc[e + 24 + eg];
        short8 v0 = *(const short8*)(gbf + (size_t)s0 * 64 + fo * 8);
        short8 v1 = *(const short8*)(gbf + (size_t)s1 * 64 + fo * 8);
        short8 v2 = *(const short8*)(gbf + (size_t)s2 * 64 + fo * 8);
        short8 v3 = *(const short8*)(gbf + (size_t)s3 * 64 + fo * 8);
#pragma unroll
        for (int j = 0; j < 8; j++) a0[j] += bf2f((unsigned short)v0[j]);
#pragma unroll
        for (int j = 0; j < 8; j++) a1[j] += bf2f((unsigned short)v1[j]);
#pragma unroll
        for (int j = 0; j < 8; j++) a2[j] += bf2f((unsigned short)v2[j]);
#pragma unroll
        for (int j = 0; j < 8; j++) a3[j] += bf2f((unsigned short)v3[j]);
    }
    if (e + 15 < end) {
        int s0 = esrc[e + eg];
        int s1 = esrc[e + 8 + eg];
        short8 v0 = *(const short8*)(gbf + (size_t)s0 * 64 + fo * 8);
        short8 v1 = *(const short8*)(gbf + (size_t)s1 * 64 + fo * 8);
#pragma unroll
        for (int j = 0; j < 8; j++) a0[j] += bf2f((unsigned short)v0[j]);
#pragma unroll
        for (int j = 0; j < 8; j++) a1[j] += bf2f((unsigned short)v1[j]);
        e += 16;
    }
    if (e + 7 < end) {
        int s = esrc[e + eg];
        short8 v = *(const short8*)(gbf + (size_t)s * 64 + fo * 8);
#pragma unroll
        for (int j = 0; j < 8; j++) a2[j] += bf2f((unsigned short)v[j]);
        e += 8;
    }
    int rem = end - e;
    if (eg < rem) {
        int s = esrc[e + eg];
        short8 v = *(const short8*)(gbf + (size_t)s * 64 + fo * 8);
#pragma unroll
        for (int j = 0; j < 8; j++) a3[j] += bf2f((unsigned short)v[j]);
    }
#pragma unroll
    for (int j = 0; j < 8; j++) {
        float s = (a0[j] + a1[j]) + (a2[j] + a3[j]);
        s += __shfl_xor(s, 8);
        s += __shfl_xor(s, 16);
        s += __shfl_xor(s, 32);
        a0[j] = s;
    }
    if (eg == 0) {
        int d = end - beg;
        float inv = (d > 0) ? 1.0f / (float)d : 0.0f;
        float ep = 1.0f + eps[3];
        const float* gr = g + (size_t)node * 64 + fo * 8;
        float4 g0 = *(const float4*)gr;
        float4 g1 = *(const float4*)(gr + 4);
        const float* blr = bl + fo * 8;
        float4 b0 = *(const float4*)blr;
        float4 b1 = *(const float4*)(blr + 4);
        float4 r0, r1;
        r0.x = ep * g0.x + a0[0] * inv + b0.x;
        r0.y = ep * g0.y + a0[1] * inv + b0.y;
        r0.z = ep * g0.z + a0[2] * inv + b0.z;
        r0.w = ep * g0.w + a0[3] * inv + b0.w;
        r1.x = ep * g1.x + a0[4] * inv + b1.x;
        r1.y = ep * g1.y + a0[5] * inv + b1.y;
        r1.z = ep * g1.z + a0[6] * inv + b1.z;
        r1.w = ep * g1.w + a0[7] * inv + b1.w;
        float* op = out + (size_t)node * 64 + fo * 8;
        *(float4*)op = r0;
        *(float4*)(op + 4) = r1;
    }
}

// ---------------- the whole pipeline: one cooperative kernel ----------------

__global__ void __launch_bounds__(BLK, 8) gin_coop(
    const int* src, const int* dst, int* cursor, int* packed, const float* X,
    const float* fcW, const float* fcb, const float* W, const float* Wl, const float* b,
    const float* bl, const float* eps, unsigned short* whi, unsigned short* wlo, float* h,
    unsigned short* bfA, unsigned short* bfB, int* row_ptr, int* esrc, float* g,
    unsigned short* gbf, float* out) {
    cg::grid_group gg = cg::this_grid();
    __shared__ unsigned smhi[16 * 64];  // 4 KB
    __shared__ unsigned smlo[16 * 64];  // 4 KB
    int G = gridDim.x;

    // ---- phase 0: binA stripes | SLP GEMM tiles | weight split (grid-stride) ----
    for (int u = blockIdx.x; u < NSTRIPE + SLPB + WSPLU; u += G) {
        if (u < NSTRIPE) {
            binA_stripe(u, src, dst, cursor, packed, (int*)smhi, (int*)smlo);
        } else if (u < NSTRIPE + SLPB) {
            slp_tile(u - NSTRIPE, X, fcW, fcb, h, bfA);
        } else {
            int i = (u - NSTRIPE - SLPB) * BLK + threadIdx.x + 16384;
            if (i < 73728) {
                float v = (i < 65536) ? W[i - 16384] : Wl[i - 65536];
                unsigned short hh = f2bf(v);
                whi[i] = hh;
                wlo[i] = f2bf(v - bf2f(hh));
            }
        }
    }
    gg.sync();

    // ---- phase 1: binB ----
    for (int u = blockIdx.x; u < NBUCK; u += G)
        binB_bucket(u, packed, cursor, row_ptr, esrc, (int*)smhi, (int*)smhi + 256,
                    (int*)smlo);
    gg.sync();

    // ---- layer 0 ----
    for (int t = blockIdx.x; t < NTILE; t += G)
        layer_tile<false>(t, h, bfA, bfB, row_ptr, esrc, eps, 0, whi + 16384, wlo + 16384,
                          b, nullptr, nullptr, nullptr, nullptr, smhi, smlo);
    gg.sync();
    // ---- layer 1 ----
    for (int t = blockIdx.x; t < NTILE; t += G)
        layer_tile<false>(t, h, bfB, bfA, row_ptr, esrc, eps, 1, whi + 32768, wlo + 32768,
                          b + 128, nullptr, nullptr, nullptr, nullptr, smhi, smlo);
    gg.sync();
    // ---- layer 2 + W_last chained through LDS (h3 never materialized) ----
    for (int t = blockIdx.x; t < NTILE; t += G)
        layer_tile<true>(t, h, bfA, nullptr, row_ptr, esrc, eps, 2, whi + 49152,
                         wlo + 49152, b + 256, whi + 65536, wlo + 65536, g, gbf, smhi,
                         smlo);
    gg.sync();

    // ---- final: out = (1+eps3)*g + mean(g) + bl, one wave per node ----
    int gw = blockIdx.x * (BLK / 64) + (threadIdx.x >> 6);
    for (int node = gw; node < N_NODES; node += G * (BLK / 64))
        agg64_node(node, g, gbf, row_ptr, esrc, eps, bl, out);
}

// ---------------- launch ----------------

extern "C" void kernel_launch(void* const* d_in, const int* in_sizes, int n_in,
                              void* d_out, int out_size, void* d_ws, size_t ws_size,
                              hipStream_t stream) {
    const int* src   = (const int*)d_in[8];
    const int* dst   = (const int*)d_in[9];
    const float* X   = (const float*)d_in[0];
    const float* fcW = (const float*)d_in[1];
    const float* fcb = (const float*)d_in[2];
    const float* W   = (const float*)d_in[3];
    const float* b   = (const float*)d_in[4];
    const float* Wl  = (const float*)d_in[5];
    const float* bl  = (const float*)d_in[6];
    const float* eps = (const float*)d_in[7];
    float* out = (float*)d_out;

    // workspace carve (~65 MB)
    float* h = (float*)d_ws;                                    // 25.6 MB (in place)
    unsigned short* bfA = (unsigned short*)(h + (size_t)N_NODES * 128);  // 12.8 MB
    unsigned short* bfB = bfA + (size_t)N_NODES * 128;                   // 12.8 MB
    unsigned short* whi = bfB + (size_t)N_NODES * 128;          // 73728 bf16
    unsigned short* wlo = whi + 73728;                          // 73728 bf16
    int* cursor  = (int*)(wlo + 73728);                         // NBUCK*CSTRIDE
    int* row_ptr = cursor + NBUCK * CSTRIDE;                    // N_NODES+1
    int* packed  = row_ptr + N_NODES + 1;                       // NBUCK*CAP (3.6 MB)
    int* esrc    = packed + NBUCK * CAP;                        // N_EDGES (3.2 MB)
    unsigned short* gbf = (unsigned short*)(esrc + N_EDGES);    // 6.4 MB
    // g overlays bfB (dead after layer-1 phase; grid sync separates)
    float* g = (float*)bfB;

    int maxb = 2;
    if (hipOccupancyMaxActiveBlocksPerMultiprocessor(&maxb, gin_coop, BLK, 0) !=
            hipSuccess ||
        maxb < 1)
        maxb = 2;
    int grid = maxb * 256;
    if (grid > MAXGRID) grid = MAXGRID;

    hipMemsetAsync(cursor, 0, NBUCK * CSTRIDE * sizeof(int), stream);

    void* args[] = {(void*)&src, (void*)&dst, (void*)&cursor, (void*)&packed, (void*)&X,
                    (void*)&fcW, (void*)&fcb, (void*)&W,      (void*)&Wl,     (void*)&b,
                    (void*)&bl,  (void*)&eps, (void*)&whi,    (void*)&wlo,    (void*)&h,
                    (void*)&bfA, (void*)&bfB, (void*)&row_ptr, (void*)&esrc,  (void*)&g,
                    (void*)&gbf, (void*)&out};
    hipLaunchCooperativeKernel((void*)gin_coop, dim3(grid), dim3(BLK), args, 0, stream);
}

// Round 13
// 386.912 us; speedup vs baseline: 2.2739x; 2.2739x over previous
//
#include <hip/hip_runtime.h>

#define N_NODES 50000
#define N_EDGES 800000
#define NBUCK 196                   // buckets of 256 nodes: bucket = dst >> 8
#define CAP 4608                    // fixed bucket capacity (mean 4082 -> 8 sigma headroom)
#define CSTRIDE 16                  // cursor padding: one cursor per 64B cache line
#define EPB 4096                    // edges per stripe-block (measured best)
#define NSTRIPE ((N_EDGES + EPB - 1) / EPB)  // 196
#define GEMMB 782                   // ceil(50000/64) SLP gemm blocks
#define WSPLB 224                   // (73728-16384)/256 weight-split tail blocks

typedef __attribute__((ext_vector_type(8))) short short8;
typedef __attribute__((ext_vector_type(4))) float float4v;

__device__ inline unsigned short f2bf(float f) {
    unsigned u = __float_as_uint(f);
    unsigned r = u + 0x7fff + ((u >> 16) & 1);
    return (unsigned short)(r >> 16);
}
__device__ inline float bf2f(unsigned short h) {
    return __uint_as_float(((unsigned)h) << 16);
}

// split 8 contiguous fp32 into bf16 hi/lo fragments
__device__ __forceinline__ void split8(const float* __restrict__ p, short8& hi8, short8& lo8) {
    float4 f0 = *(const float4*)p;
    float4 f1 = *(const float4*)(p + 4);
    float fv[8] = {f0.x, f0.y, f0.z, f0.w, f1.x, f1.y, f1.z, f1.w};
#pragma unroll
    for (int j = 0; j < 8; j++) {
        unsigned short hh = f2bf(fv[j]);
        hi8[j] = (short)hh;
        lo8[j] = (short)f2bf(fv[j] - bf2f(hh));
    }
}

// ---------------- deep-ILP neighbor gather (16 edges in flight) ----------------
// lane = (eg = lane>>4 edge slot, fo = lane&15 feat quad). After the call every
// lane holds the full neighbor-sum for feats fo*8..fo*8+7 in a0[8].

__device__ __forceinline__ void gather_sum(const unsigned short* __restrict__ bf,
                                           const int* __restrict__ esrc, int beg, int end,
                                           int eg, int fo, float a0[8]) {
    float a1[8], a2[8], a3[8];
#pragma unroll
    for (int j = 0; j < 8; j++) { a0[j] = 0.f; a1[j] = 0.f; a2[j] = 0.f; a3[j] = 0.f; }
    int e = beg;
    for (; e + 15 < end; e += 16) {
        int s0 = esrc[e + eg];
        int s1 = esrc[e + 4 + eg];
        int s2 = esrc[e + 8 + eg];
        int s3 = esrc[e + 12 + eg];
        short8 v0 = *(const short8*)(bf + (size_t)s0 * 128 + fo * 8);
        short8 v1 = *(const short8*)(bf + (size_t)s1 * 128 + fo * 8);
        short8 v2 = *(const short8*)(bf + (size_t)s2 * 128 + fo * 8);
        short8 v3 = *(const short8*)(bf + (size_t)s3 * 128 + fo * 8);
#pragma unroll
        for (int j = 0; j < 8; j++) a0[j] += bf2f((unsigned short)v0[j]);
#pragma unroll
        for (int j = 0; j < 8; j++) a1[j] += bf2f((unsigned short)v1[j]);
#pragma unroll
        for (int j = 0; j < 8; j++) a2[j] += bf2f((unsigned short)v2[j]);
#pragma unroll
        for (int j = 0; j < 8; j++) a3[j] += bf2f((unsigned short)v3[j]);
    }
    if (e + 7 < end) {
        int s0 = esrc[e + eg];
        int s1 = esrc[e + 4 + eg];
        short8 v0 = *(const short8*)(bf + (size_t)s0 * 128 + fo * 8);
        short8 v1 = *(const short8*)(bf + (size_t)s1 * 128 + fo * 8);
#pragma unroll
        for (int j = 0; j < 8; j++) a0[j] += bf2f((unsigned short)v0[j]);
#pragma unroll
        for (int j = 0; j < 8; j++) a1[j] += bf2f((unsigned short)v1[j]);
        e += 8;
    }
    if (e + 3 < end) {
        int s = esrc[e + eg];
        short8 v = *(const short8*)(bf + (size_t)s * 128 + fo * 8);
#pragma unroll
        for (int j = 0; j < 8; j++) a2[j] += bf2f((unsigned short)v[j]);
        e += 4;
    }
    int rem = end - e;
    if (eg < rem) {
        int s = esrc[e + eg];
        short8 v = *(const short8*)(bf + (size_t)s * 128 + fo * 8);
#pragma unroll
        for (int j = 0; j < 8; j++) a3[j] += bf2f((unsigned short)v[j]);
    }
#pragma unroll
    for (int j = 0; j < 8; j++) {
        float s = (a0[j] + a1[j]) + (a2[j] + a3[j]);
        s += __shfl_xor(s, 16);
        s += __shfl_xor(s, 32);
        a0[j] = s;
    }
}

// ---------------- SLP GEMM body (A and B both fp32, split inline) ----------------

__device__ __forceinline__ void slp_gemm(int bx, const float* __restrict__ X,
                                         const float* __restrict__ fcW,
                                         const float* __restrict__ fcb, float* __restrict__ h,
                                         unsigned short* __restrict__ hbf) {
    int wave = threadIdx.x >> 6;
    int lane = threadIdx.x & 63;
    int m = lane & 15;
    int quad = lane >> 4;
    int r0 = bx * 64 + wave * 16;
    int rowA = r0 + m;
    if (rowA >= N_NODES) rowA = N_NODES - 1;  // clamp loads; stores guarded

    short8 ahi[4], alo[4];
    const float* arow = X + (size_t)rowA * 128 + quad * 8;
#pragma unroll
    for (int kc = 0; kc < 4; kc++) split8(arow + kc * 32, ahi[kc], alo[kc]);

#pragma unroll
    for (int nt = 0; nt < 8; nt++) {
        int n = nt * 16 + m;
        const float* brow = fcW + (size_t)n * 128 + quad * 8;
        float4v acc = {0.f, 0.f, 0.f, 0.f};
#pragma unroll
        for (int kc = 0; kc < 4; kc++) {
            short8 bh, bl;
            split8(brow + kc * 32, bh, bl);
            acc = __builtin_amdgcn_mfma_f32_16x16x32_bf16(ahi[kc], bh, acc, 0, 0, 0);
            acc = __builtin_amdgcn_mfma_f32_16x16x32_bf16(alo[kc], bh, acc, 0, 0, 0);
            acc = __builtin_amdgcn_mfma_f32_16x16x32_bf16(ahi[kc], bl, acc, 0, 0, 0);
        }
        float bv = fcb[n];
#pragma unroll
        for (int i = 0; i < 4; i++) {
            int r = r0 + quad * 4 + i;
            if (r < N_NODES) {
                float v = fmaxf(acc[i] + bv, 0.f);
                h[(size_t)r * 128 + n] = v;
                hbf[(size_t)r * 128 + n] = f2bf(v);
            }
        }
    }
}

// ---------------- K1: binning (196) + SLP GEMM (782) + weight split (224) ----------

__global__ void __launch_bounds__(256) fused_binA_gemm(
    const int* __restrict__ src, const int* __restrict__ dst, int* __restrict__ cursor,
    int* __restrict__ packed, const float* __restrict__ X, const float* __restrict__ fcW,
    const float* __restrict__ fcb, const float* __restrict__ W, const float* __restrict__ Wl,
    unsigned short* __restrict__ whi, unsigned short* __restrict__ wlo, float* __restrict__ h,
    unsigned short* __restrict__ hbf) {
    int bx = blockIdx.x;
    if (bx < NSTRIPE) {
        __shared__ int lcount[256];
        __shared__ int lbase[256];
        int t = threadIdx.x;
        lcount[t] = 0;
        __syncthreads();
        int base = bx * EPB + t;
#pragma unroll 4
        for (int k = 0; k < EPB / 256; k++) {
            int i = base + k * 256;
            if (i < N_EDGES) atomicAdd(&lcount[((unsigned)dst[i]) >> 8], 1);
        }
        __syncthreads();
        if (t < NBUCK) {
            lbase[t] = t * CAP + atomicAdd(&cursor[t * CSTRIDE], lcount[t]);
            lcount[t] = 0;
        }
        __syncthreads();
#pragma unroll 4
        for (int k = 0; k < EPB / 256; k++) {
            int i = base + k * 256;
            if (i < N_EDGES) {
                int d = dst[i];
                int wb = ((unsigned)d) >> 8;
                int p = lbase[wb] + atomicAdd(&lcount[wb], 1);
                if (p < (wb + 1) * CAP)  // overflow guard (never expected)
                    packed[p] = ((d & 255) << 16) | src[i];
            }
        }
    } else if (bx < NSTRIPE + GEMMB) {
        slp_gemm(bx - NSTRIPE, X, fcW, fcb, h, hbf);
    } else {
        // weight split for layers 1-3 + W_last: whi/wlo[16384..73728).
        // Consumed only by LATER dispatches -> no intra-grid ordering hazard.
        int i = (bx - NSTRIPE - GEMMB) * 256 + threadIdx.x + 16384;
        if (i < 73728) {
            float v = (i < 65536) ? W[i - 16384] : Wl[i - 65536];
            unsigned short hh = f2bf(v);
            whi[i] = hh;
            wlo[i] = f2bf(v - bf2f(hh));
        }
    }
}

// ---------------- K2: scan (redundant per block) + per-bucket counting sort ----------

__global__ void __launch_bounds__(256) binB_kernel(const int* __restrict__ packed,
                                                   const int* __restrict__ cursor,
                                                   int* __restrict__ row_ptr,
                                                   int* __restrict__ esrc) {
    __shared__ int sm[256];
    __shared__ int cntS[256];
    __shared__ int curs[256];
    int b = blockIdx.x;
    int t = threadIdx.x;
    int cnt = (t < NBUCK) ? cursor[t * CSTRIDE] : 0;
    cntS[t] = cnt;
    sm[t] = cnt;
    __syncthreads();
    for (int o = 1; o < 256; o <<= 1) {
        int x = sm[t];
        int a = (t >= o) ? sm[t - o] : 0;
        __syncthreads();
        sm[t] = x + a;
        __syncthreads();
    }
    int w0 = sm[b] - cntS[b];
    int mycnt = cntS[b];
    int total = sm[NBUCK - 1];
    __syncthreads();
    if (b == NBUCK - 1 && t == 0) row_ptr[N_NODES] = total;
    int e0r = b * CAP, e1r = b * CAP + mycnt;
    curs[t] = 0;
    __syncthreads();
    for (int i = e0r + t; i < e1r; i += 256) atomicAdd(&curs[((unsigned)packed[i]) >> 16], 1);
    __syncthreads();
    int v = curs[t];
    sm[t] = v;
    __syncthreads();
    for (int o = 1; o < 256; o <<= 1) {
        int x = sm[t];
        int a = (t >= o) ? sm[t - o] : 0;
        __syncthreads();
        sm[t] = x + a;
        __syncthreads();
    }
    int excl = sm[t] - v;
    curs[t] = excl;
    int node = b * 256 + t;
    if (node < N_NODES) row_ptr[node] = w0 + excl;
    __syncthreads();
    for (int i = e0r + t; i < e1r; i += 256) {
        unsigned w = (unsigned)packed[i];
        int p = atomicAdd(&curs[w >> 16], 1);
        esrc[w0 + p] = (int)(w & 0xFFFFu);
    }
}

// ---------------- K3/K4/K5: fused GIN layer -------------------------------------
// 512 threads = 8 waves, 16 nodes/block (50000 = 3125*16 exactly, no tail).
// Phase 1: wave w gathers nodes w and w+8 (deep-ILP, 16 edges in flight), computes
//   u = (1+eps)*h + mean, splits to bf16 hi/lo, deposits into XOR-swizzled LDS.
// Phase 2: wave w computes output col-tile w (16 cols) of the 16-row tile via MFMA,
//   writes h fp32 (in place, block-local rows) + bf16 payload (ping-pong buffer).
// LAST variant: phase-2 result (h3) goes back into LDS; phase 3 multiplies by
//   W_last (waves 0-3), writing g fp32 + gbf. h3 never materialized.
// LDS swizzle: 8-feat group G of row r stored at G ^ (r&7).

template <bool LAST>
__global__ void __launch_bounds__(512) layer_fused(
    float* __restrict__ hio, const unsigned short* __restrict__ bfin,
    unsigned short* __restrict__ bfout, const int* __restrict__ row_ptr,
    const int* __restrict__ esrc, const float* __restrict__ eps, int layer,
    const unsigned short* __restrict__ Whi, const unsigned short* __restrict__ Wlo,
    const float* __restrict__ bias, const unsigned short* __restrict__ Lhi,
    const unsigned short* __restrict__ Llo, float* __restrict__ g,
    unsigned short* __restrict__ gbf) {
    __shared__ unsigned lds_hi[16 * 64];  // 16 rows x 64 dword feat-pairs
    __shared__ unsigned lds_lo[16 * 64];
    int tid = threadIdx.x;
    int wv = tid >> 6;
    int lane = tid & 63;
    int eg = lane >> 4;
    int fo = lane & 15;
    int nb = blockIdx.x * 16;
    float ep = 1.0f + eps[layer];

    // ---- phase 1 ----
#pragma unroll
    for (int half = 0; half < 2; half++) {
        int r = wv + half * 8;  // local row 0..15
        int node = nb + r;      // always < N_NODES (exact tiling)
        int beg = __builtin_amdgcn_readfirstlane(row_ptr[node]);
        int end = __builtin_amdgcn_readfirstlane(row_ptr[node + 1]);
        float a0[8];
        gather_sum(bfin, esrc, beg, end, eg, fo, a0);
        if (eg == 0) {
            int d = end - beg;
            float inv = (d > 0) ? 1.0f / (float)d : 0.0f;
            const float* hr = hio + (size_t)node * 128 + fo * 8;
            float4 h0 = *(const float4*)hr;
            float4 h1 = *(const float4*)(hr + 4);
            float hv[8] = {h0.x, h0.y, h0.z, h0.w, h1.x, h1.y, h1.z, h1.w};
            unsigned hip[4], lop[4];
#pragma unroll
            for (int jj = 0; jj < 4; jj++) {
                float ux = ep * hv[2 * jj] + a0[2 * jj] * inv;
                float uy = ep * hv[2 * jj + 1] + a0[2 * jj + 1] * inv;
                unsigned short uh0 = f2bf(ux), uh1 = f2bf(uy);
                hip[jj] = (unsigned)uh0 | ((unsigned)uh1 << 16);
                lop[jj] = (unsigned)f2bf(ux - bf2f(uh0)) | ((unsigned)f2bf(uy - bf2f(uh1)) << 16);
            }
            int grp = fo ^ (r & 7);
            *(uint4*)&lds_hi[r * 64 + grp * 4] = make_uint4(hip[0], hip[1], hip[2], hip[3]);
            *(uint4*)&lds_lo[r * 64 + grp * 4] = make_uint4(lop[0], lop[1], lop[2], lop[3]);
        }
    }
    __syncthreads();

    // ---- phase 2: wave wv owns col-tile wv ----
    int m = lane & 15;
    int quad = lane >> 4;
    short8 ahi[4], alo[4];
#pragma unroll
    for (int kc = 0; kc < 4; kc++) {
        int grp = (quad + kc * 4) ^ (m & 7);
        ahi[kc] = *(const short8*)&lds_hi[m * 64 + grp * 4];
        alo[kc] = *(const short8*)&lds_lo[m * 64 + grp * 4];
    }
    int n = wv * 16 + m;
    const unsigned short* bhp = Whi + (size_t)n * 128 + quad * 8;
    const unsigned short* blp = Wlo + (size_t)n * 128 + quad * 8;
    float4v acc = {0.f, 0.f, 0.f, 0.f};
#pragma unroll
    for (int kc = 0; kc < 4; kc++) {
        short8 bh = *(const short8*)(bhp + kc * 32);
        short8 bl = *(const short8*)(blp + kc * 32);
        acc = __builtin_amdgcn_mfma_f32_16x16x32_bf16(ahi[kc], bh, acc, 0, 0, 0);
        acc = __builtin_amdgcn_mfma_f32_16x16x32_bf16(alo[kc], bh, acc, 0, 0, 0);
        acc = __builtin_amdgcn_mfma_f32_16x16x32_bf16(ahi[kc], bl, acc, 0, 0, 0);
    }
    float bv = bias[n];

    if (!LAST) {
#pragma unroll
        for (int i = 0; i < 4; i++) {
            int rg = nb + quad * 4 + i;
            float v = fmaxf(acc[i] + bv, 0.f);
            hio[(size_t)rg * 128 + n] = v;
            bfout[(size_t)rg * 128 + n] = f2bf(v);
        }
    } else {
        // h3 back into LDS (barrier first: phase-2 reads must drain)
        __syncthreads();
        unsigned short* lh = (unsigned short*)lds_hi;
        unsigned short* ll = (unsigned short*)lds_lo;
#pragma unroll
        for (int i = 0; i < 4; i++) {
            int rl = quad * 4 + i;
            float v = fmaxf(acc[i] + bv, 0.f);
            unsigned short vh = f2bf(v);
            unsigned short vl = f2bf(v - bf2f(vh));
            int gidx = (n >> 3) ^ (rl & 7);
            int us = rl * 128 + gidx * 8 + (n & 7);
            lh[us] = vh;
            ll[us] = vl;
        }
        __syncthreads();
        // ---- phase 3: waves 0-3 -> g = h3 @ Wl^T (64 cols) ----
        if (wv < 4) {
            short8 a2h[4], a2l[4];
#pragma unroll
            for (int kc = 0; kc < 4; kc++) {
                int grp = (quad + kc * 4) ^ (m & 7);
                a2h[kc] = *(const short8*)&lds_hi[m * 64 + grp * 4];
                a2l[kc] = *(const short8*)&lds_lo[m * 64 + grp * 4];
            }
            int n2 = wv * 16 + m;
            const unsigned short* lhp = Lhi + (size_t)n2 * 128 + quad * 8;
            const unsigned short* llp = Llo + (size_t)n2 * 128 + quad * 8;
            float4v a2 = {0.f, 0.f, 0.f, 0.f};
#pragma unroll
            for (int kc = 0; kc < 4; kc++) {
                short8 bh = *(const short8*)(lhp + kc * 32);
                short8 bl = *(const short8*)(llp + kc * 32);
                a2 = __builtin_amdgcn_mfma_f32_16x16x32_bf16(a2h[kc], bh, a2, 0, 0, 0);
                a2 = __builtin_amdgcn_mfma_f32_16x16x32_bf16(a2l[kc], bh, a2, 0, 0, 0);
                a2 = __builtin_amdgcn_mfma_f32_16x16x32_bf16(a2h[kc], bl, a2, 0, 0, 0);
            }
#pragma unroll
            for (int i = 0; i < 4; i++) {
                int rg = nb + quad * 4 + i;
                float v = a2[i];
                g[(size_t)rg * 64 + n2] = v;
                gbf[(size_t)rg * 64 + n2] = f2bf(v);
            }
        }
    }
}

// ---------------- K6: out = (1+eps3)*g + mean(g) + bl --------------------------
// 8-wide row gather; 32 edges in flight (4 sets).

__global__ void __launch_bounds__(256) agg64_out(
    const float* __restrict__ g, const unsigned short* __restrict__ gbf,
    const int* __restrict__ row_ptr, const int* __restrict__ esrc,
    const float* __restrict__ eps, const float* __restrict__ bl, float* __restrict__ out) {
    int gtid = blockIdx.x * 256 + threadIdx.x;
    int node = gtid >> 6;
    if (node >= N_NODES) return;
    int lane = threadIdx.x & 63;
    node = __builtin_amdgcn_readfirstlane(node);
    int beg = __builtin_amdgcn_readfirstlane(row_ptr[node]);
    int end = __builtin_amdgcn_readfirstlane(row_ptr[node + 1]);
    int eg = lane >> 3;  // edge slot 0..7
    int fo = lane & 7;   // feat quad: feats fo*8 .. fo*8+7

    float a0[8] = {0.f, 0.f, 0.f, 0.f, 0.f, 0.f, 0.f, 0.f};
    float a1[8] = {0.f, 0.f, 0.f, 0.f, 0.f, 0.f, 0.f, 0.f};
    float a2[8] = {0.f, 0.f, 0.f, 0.f, 0.f, 0.f, 0.f, 0.f};
    float a3[8] = {0.f, 0.f, 0.f, 0.f, 0.f, 0.f, 0.f, 0.f};
    int e = beg;
    for (; e + 31 < end; e += 32) {
        int s0 = esrc[e + eg];
        int s1 = esrc[e + 8 + eg];
        int s2 = esrc[e + 16 + eg];
        int s3 = esrc[e + 24 + eg];
        short8 v0 = *(const short8*)(gbf + (size_t)s0 * 64 + fo * 8);
        short8 v1 = *(const short8*)(gbf + (size_t)s1 * 64 + fo * 8);
        short8 v2 = *(const short8*)(gbf + (size_t)s2 * 64 + fo * 8);
        short8 v3 = *(const short8*)(gbf + (size_t)s3 * 64 + fo * 8);
#pragma unroll
        for (int j = 0; j < 8; j++) a0[j] += bf2f((unsigned short)v0[j]);
#pragma unroll
        for (int j = 0; j < 8; j++) a1[j] += bf2f((unsigned short)v1[j]);
#pragma unroll
        for (int j = 0; j < 8; j++) a2[j] += bf2f((unsigned short)v2[j]);
#pragma unroll
        for (int j = 0; j < 8; j++) a3[j] += bf2f((unsigned short)v3[j]);
    }
    if (e + 15 < end) {
        int s0 = esrc[e + eg];
        int s1 = esrc[e + 8 + eg];
        short8 v0 = *(const short8*)(gbf + (size_t)s0 * 64 + fo * 8);
        short8 v1 = *(const short8*)(gbf + (size_t)s1 * 64 + fo * 8);
#pragma unroll
        for (int j = 0; j < 8; j++) a0[j] += bf2f((unsigned short)v0[j]);
#pragma unroll
        for (int j = 0; j < 8; j++) a1[j] += bf2f((unsigned short)v1[j]);
        e += 16;
    }
    if (e + 7 < end) {
        int s = esrc[e + eg];
        short8 v = *(const short8*)(gbf + (size_t)s * 64 + fo * 8);
#pragma unroll
        for (int j = 0; j < 8; j++) a2[j] += bf2f((unsigned short)v[j]);
        e += 8;
    }
    int rem = end - e;
    if (eg < rem) {
        int s = esrc[e + eg];
        short8 v = *(const short8*)(gbf + (size_t)s * 64 + fo * 8);
#pragma unroll
        for (int j = 0; j < 8; j++) a3[j] += bf2f((unsigned short)v[j]);
    }
#pragma unroll
    for (int j = 0; j < 8; j++) {
        float s = (a0[j] + a1[j]) + (a2[j] + a3[j]);
        s += __shfl_xor(s, 8);
        s += __shfl_xor(s, 16);
        s += __shfl_xor(s, 32);
        a0[j] = s;
    }
    if (eg == 0) {
        int d = end - beg;
        float inv = (d > 0) ? 1.0f / (float)d : 0.0f;
        float ep = 1.0f + eps[3];
        const float* gr = g + (size_t)node * 64 + fo * 8;
        float4 g0 = *(const float4*)gr;
        float4 g1 = *(const float4*)(gr + 4);
        const float* blr = bl + fo * 8;
        float4 b0 = *(const float4*)blr;
        float4 b1 = *(const float4*)(blr + 4);
        float4 r0, r1;
        r0.x = ep * g0.x + a0[0] * inv + b0.x;
        r0.y = ep * g0.y + a0[1] * inv + b0.y;
        r0.z = ep * g0.z + a0[2] * inv + b0.z;
        r0.w = ep * g0.w + a0[3] * inv + b0.w;
        r1.x = ep * g1.x + a0[4] * inv + b1.x;
        r1.y = ep * g1.y + a0[5] * inv + b1.y;
        r1.z = ep * g1.z + a0[6] * inv + b1.z;
        r1.w = ep * g1.w + a0[7] * inv + b1.w;
        float* op = out + (size_t)node * 64 + fo * 8;
        *(float4*)op = r0;
        *(float4*)(op + 4) = r1;
    }
}

// ---------------- launch ----------------

extern "C" void kernel_launch(void* const* d_in, const int* in_sizes, int n_in,
                              void* d_out, int out_size, void* d_ws, size_t ws_size,
                              hipStream_t stream) {
    const float* X   = (const float*)d_in[0];
    const float* fcW = (const float*)d_in[1];
    const float* fcb = (const float*)d_in[2];
    const float* W   = (const float*)d_in[3];
    const float* b   = (const float*)d_in[4];
    const float* Wl  = (const float*)d_in[5];
    const float* bl  = (const float*)d_in[6];
    const float* eps = (const float*)d_in[7];
    const int* src   = (const int*)d_in[8];
    const int* dst   = (const int*)d_in[9];
    float* out = (float*)d_out;

    // workspace carve (~65 MB); u planes eliminated entirely (u lives in LDS now)
    float* h = (float*)d_ws;                                    // 50000*128 f32 (in place)
    unsigned short* bfA = (unsigned short*)(h + (size_t)N_NODES * 128);  // 12.8MB payload ping
    unsigned short* bfB = bfA + (size_t)N_NODES * 128;                   // 12.8MB payload pong
    unsigned short* whi = bfB + (size_t)N_NODES * 128;          // 73728 bf16 (only 16384.. used)
    unsigned short* wlo = whi + 73728;                          // 73728 bf16
    int* cursor  = (int*)(wlo + 73728);                         // NBUCK*CSTRIDE (line-padded)
    int* row_ptr = cursor + NBUCK * CSTRIDE;                    // N_NODES+1
    int* packed  = row_ptr + N_NODES + 1;                       // NBUCK*CAP sparse
    int* esrc    = packed + NBUCK * CAP;                        // N_EDGES
    unsigned short* gbf = (unsigned short*)(esrc + N_EDGES);    // 6.4MB
    // g overlays bfB: bfB's last reader is layer 1 (finished before layer 2 runs).
    float* g = (float*)bfB;

    const int agg_blocks = (N_NODES * 64 + 255) / 256;   // 12500
    const int layer_blocks = N_NODES / 16;               // 3125 (exact)

    hipMemsetAsync(cursor, 0, NBUCK * CSTRIDE * sizeof(int), stream);
    fused_binA_gemm<<<NSTRIPE + GEMMB + WSPLB, 256, 0, stream>>>(
        src, dst, cursor, packed, X, fcW, fcb, W, Wl, whi, wlo, h, bfA);
    binB_kernel<<<NBUCK, 256, 0, stream>>>(packed, cursor, row_ptr, esrc);

    // layers 0,1: fused agg+GEMM (payload ping-pong, h in place)
    layer_fused<false><<<layer_blocks, 512, 0, stream>>>(
        h, bfA, bfB, row_ptr, esrc, eps, 0, whi + 16384, wlo + 16384, b,
        nullptr, nullptr, nullptr, nullptr);
    layer_fused<false><<<layer_blocks, 512, 0, stream>>>(
        h, bfB, bfA, row_ptr, esrc, eps, 1, whi + 32768, wlo + 32768, b + 128,
        nullptr, nullptr, nullptr, nullptr);
    // layer 2 + W_last chained through LDS (h3 never materialized)
    layer_fused<true><<<layer_blocks, 512, 0, stream>>>(
        h, bfA, nullptr, row_ptr, esrc, eps, 2, whi + 49152, wlo + 49152, b + 256,
        whi + 65536, wlo + 65536, g, gbf);

    // out = (1+eps3)*g + mean(g) + bl
    agg64_out<<<agg_blocks, 256, 0, stream>>>(g, gbf, row_ptr, esrc, eps, bl, out);
}